// Round 17
// baseline (58.069 us; speedup 1.0000x reference)
//
#include <hip/hip_runtime.h>
#include <hip/hip_bf16.h>

#define SEQ   512
#define LPAD  64
#define RPAD  68
#define TOT   (SEQ + LPAD + RPAD)   // 644 float4 per sequence
#define C1f   14.426950408889634f    // 1/(gamma*ln2), gamma=0.1
#define K1f   0.069314718055994531f  // gamma*ln2

#if __has_builtin(__builtin_amdgcn_exp2f)
#define EXP2(x) __builtin_amdgcn_exp2f(x)
#else
#define EXP2(x) exp2f(x)
#endif

#define SB() __builtin_amdgcn_sched_barrier(0)

__device__ __forceinline__ float cost4(float4 X, float4 Y) {
  return fabsf(X.x - Y.x) + fabsf(X.y - Y.y) + fabsf(X.z - Y.z) + fabsf(X.w - Y.w);
}

// f64 lane shifts via DPP wave shifts: VALU, 0-fill at edges (0 == exp-domain BIG).
__device__ __forceinline__ double dshr1(double x) {  // lane t <- lane t+1; lane63 <- 0
  int lo = __builtin_amdgcn_update_dpp(0, __double2loint(x), 0x138, 0xF, 0xF, true);
  int hi = __builtin_amdgcn_update_dpp(0, __double2hiint(x), 0x138, 0xF, 0xF, true);
  return __hiloint2double(hi, lo);
}
__device__ __forceinline__ double dshl1(double x) {  // lane t <- lane t-1; lane0 <- 0
  int lo = __builtin_amdgcn_update_dpp(0, __double2loint(x), 0x130, 0xF, 0xF, true);
  int hi = __builtin_amdgcn_update_dpp(0, __double2hiint(x), 0x130, 0xF, 0xF, true);
  return __hiloint2double(hi, lo);
}
__device__ __forceinline__ double pow2i(int k) {     // 2^k exactly, |k| <= ~500
  union { unsigned long long u; double d; } v;
  v.u = ((unsigned long long)(1023 + k)) << 52;
  return v.d;
}

// ---- 1 cell/lane, band u = t in [0,63]; f64 exp-domain DP (R14 algebra) ----
// pair n covers diags p=2n+1 (odd) and p=2n+2 (even).
//   odd  cell: i = n+t-31, j = n-t+32; neighbors: diag=dA, left=dB, up=dshl1(dB)
//   even cell: i = n+t-30, j = n-t+32; neighbors: diag=dB, up=nA, left=dshr1(nA)
// windows: X0 = x[n+t-31], X1 = x[n+t-30], Y0 = y[n-t+32]
// 6 rotating slots; pair m -> slot m%6. TWO pairs per SB scheduling region.
#define DECLS(s) \
  float4 X0##s, X1##s, Y0##s; \
  double Po##s, Pe##s; \
  int k1##s, k2##s;

#define LOADW(s, m) do { \
    X0##s = pX[(m)]; X1##s = pX[(m) + 1]; Y0##s = pY[(m)]; } while (0)

// P factors for the pair in slot s with scale bump folded into the exp2 arg.
#define COMPP(s, bump) do { \
    k1##s = (bump) >> 1; k2##s = (bump) - k1##s; \
    float _f1 = (float)k1##s, _f2 = (float)k2##s; \
    Po##s = (double)EXP2(fmaf(cost4(X0##s, Y0##s), -C1f, _f1)); \
    Pe##s = (double)EXP2(fmaf(cost4(X1##s, Y0##s), -C1f, _f2)); } while (0)

// f64 recurrence for one pair; sp = previous pair's slot (supplies k2prev).
#define CHAIN(s, sp) do { \
    double _s2p = pow2i(k2##sp), _s1c = pow2i(k1##s); \
    double _up = dshl1(dB); \
    double _nA = Po##s * fma(dA, _s2p, dB + _up); \
    double _lf = dshr1(_nA); \
    double _nB = Pe##s * fma(dB, _s1c, _nA + _lf); \
    dA = _nA; dB = _nB; } while (0)

// lag-queue residual renorm feedback, once per region (2 pairs).
// center cell = lane31 even diag (n+1,n+1), always valid.
#define FEEDBACK() do { \
    int _hib = __builtin_amdgcn_readlane(__double2hiint(dB), 31); \
    int _def = 1023 - ((_hib >> 20) & 0x7ff); \
    Ktot += bq0; \
    int _nb = _def - bq1; _nb = _nb < -250 ? -250 : (_nb > 250 ? 250 : _nb); \
    bq0 = bq1; bq1 = _nb; } while (0)

// group k (pairs 2k,2k+1 chained): A=slot(2k), B=A+1, C=A+2, D=A+3, E=A+4,
// F=A+5 (mod 6). F also = slot(2k-1), whose k2 is pair 2k-1's (COMPP'd two
// groups ago; LOADW(F) below only touches windows, not k's).
#define GROUP(A, B, C, D, E, F, m) do { \
    SB(); \
    LOADW(E, (m));     LOADW(F, (m) + 1); \
    COMPP(C, bq1);     COMPP(D, 0); \
    CHAIN(A, F);       CHAIN(B, A); \
    FEEDBACK(); } while (0)

// Last-block combine: ws[0..95]=v, ws[96..98]=loss sums, counter at ws[128].
// Executed by the first wave (t<64) of every block after its ws writes.
#define TAIL_COMBINE() do { \
    __threadfence(); \
    unsigned _last = 0; \
    if (t == 0) _last = (atomicAdd((unsigned*)(ws + 128), 1u) == 96u) ? 1u : 0u; \
    _last = (unsigned)__shfl((int)_last, 0, 64); \
    if (_last) { \
      __threadfence(); \
      float _vn = 0.f; \
      if (t < 32) _vn = ws[t] - 0.5f * (ws[32 + t] + ws[64 + t]); \
      _vn += __shfl_down(_vn, 16, 32); \
      _vn += __shfl_down(_vn,  8, 32); \
      _vn += __shfl_down(_vn,  4, 32); \
      _vn += __shfl_down(_vn,  2, 32); \
      _vn += __shfl_down(_vn,  1, 32); \
      if (t == 0) { \
        float _recon = _vn * (1.0f / 1024.0f); \
        float _kl    = ws[96] * (1.0f / 32.0f); \
        float _aux   = ws[97] * (1.0f / 32.0f); \
        float _tr    = ws[98] * (1.0f / 32.0f); \
        out[0] = _recon + _kl + 0.1f * _aux + 0.5f * _tr; \
        out[1] = _recon; \
        out[2] = _kl; \
        out[3] = _aux; \
        out[4] = _tr; \
      } \
    } } while (0)

// Blocks 0..95: banded soft-DTW per extended batch element -> ws[b].
// Block 96: KL + transition-count losses -> ws[96..98]. Last block combines.
__global__ __launch_bounds__(256, 1) void sdtw_fused_kernel(
    const float* __restrict__ at,    // [32,512,4]
    const float* __restrict__ mu,    // [32,64]
    const float* __restrict__ lv,    // [32,64]
    const float* __restrict__ ptc,   // [32,1]
    const float* __restrict__ gt,    // [32,512,4]
    float* __restrict__ ws,          // workspace (see TAIL_COMBINE)
    float* __restrict__ out)         // [5]
{
  __shared__ float4 sx[TOT];
  __shared__ float4 sy[TOT];
  __shared__ float s_g[32], s_ps[32], s_kl[32];

  const int blk = blockIdx.x;
  const int t   = threadIdx.x;

  if (blk < 96) {
    const float* xs;
    const float* ys;
    if (blk < 32)      { xs = at + (size_t)blk        * SEQ * 4; ys = gt + (size_t)blk * SEQ * 4; }
    else if (blk < 64) { xs = at + (size_t)(blk - 32) * SEQ * 4; ys = xs; }
    else               { xs = gt + (size_t)(blk - 64) * SEQ * 4; ys = xs; }

    for (int i = t; i < LPAD; i += 256) {
      sx[i] = make_float4(0.f, 0.f, 0.f, 0.f);
      sy[i] = make_float4(0.f, 0.f, 0.f, 0.f);
    }
    for (int i = LPAD + SEQ + t; i < TOT; i += 256) {
      sx[i] = make_float4(0.f, 0.f, 0.f, 0.f);
      sy[i] = make_float4(0.f, 0.f, 0.f, 0.f);
    }
    for (int i = t; i < SEQ; i += 256) {
      sx[LPAD + i] = ((const float4*)xs)[i];
      sy[LPAD + i] = ((const float4*)ys)[i];
    }
    __syncthreads();
    if (t >= 64) return;   // single wave runs the wavefront; no more barriers

    const float4* sxp = sx + LPAD;
    const float4* syp = sy + LPAD;
    const float4* pX = sxp + (t - 31);   // pX[m] = x[m+t-31]
    const float4* pY = syp + (32 - t);   // pY[m] = y[m-t+32]

    // seed: diag 0 = (0,0) at lane31 (even diag of pair -1; its slot is 5, k2_5=0)
    float a0 = -C1f * cost4(sxp[0], syp[0]);
    int   n0 = (int)floorf(a0);
    double e00 = (double)EXP2(a0 - (float)n0);
    double dA = 0.0;
    double dB = (t == 31) ? e00 : 0.0;
    int Ktot = -n0;
    int bq0 = 0, bq1 = 0;

    DECLS(0) DECLS(1) DECLS(2) DECLS(3) DECLS(4) DECLS(5)
    k25 = 0;   // pair -1's even bump (read by CHAIN(0,5) in group 0)
    k15 = 0;

    // prologue: windows for pairs 0..3; P for pairs 0,1 (bumps 0)
    LOADW(0, 0); LOADW(1, 1); LOADW(2, 2); LOADW(3, 3);
    COMPP(0, 0); COMPP(1, 0);

    // steady: 255 groups (pairs 0..509), 3 groups per iteration (6 pairs)
    #pragma unroll 1
    for (int g = 0; g < 85; ++g) {
      const int m = 6 * g;
      GROUP(0, 1, 2, 3, 4, 5, m + 4);
      GROUP(2, 3, 4, 5, 0, 1, m + 6);
      GROUP(4, 5, 0, 1, 2, 3, m + 8);
    }
    // epilogue: pair 510 (slot 0; prev pair 509 in slot 5)
    SB();
    CHAIN(0, 5);
    Ktot += bq0;   // bump consumed by COMPP(pair 510), landed in the chain above

    if (t == 31) {
      // final cell (511,511) = even diag of pair 510, lane31
      // v = -gamma*ln(E_true) = -K1f*(log2(stored) - Ktot)
      unsigned long long bits = __double_as_longlong(dB);
      int ee = (int)((bits >> 52) & 0x7ffull);
      double mant = __longlong_as_double((bits & 0xFFFFFFFFFFFFFull) | (1023ull << 52));
      double l2 = (double)(ee - 1023) + (double)__log2f((float)mant);
      ws[blk] = (float)(-(double)K1f * (l2 - (double)Ktot));
    }
    TAIL_COMBINE();
    return;
  }

  // ---------- loss block (blk == 96), 256 threads: 8 per batch element ----------
  const int b = t >> 3, seg = t & 7;

  float s = 0.f;
  {
    const float* mb = mu + b * 64 + seg * 8;
    const float* lb = lv + b * 64 + seg * 8;
    #pragma unroll
    for (int z = 0; z < 8; ++z) {
      float m = mb[z], l = lb[z];
      s += 1.0f + l - m * m - __expf(l);
    }
  }
  s += __shfl_down(s, 4, 8);
  s += __shfl_down(s, 2, 8);
  s += __shfl_down(s, 1, 8);

  float g = 0.f, ps = 0.f;
  {
    const int n0 = seg * 64;
    const int nstart = (seg == 0) ? 1 : n0;
    const float* gb = gt + (size_t)b * SEQ * 4 + 2;
    const float* ab = at + (size_t)b * SEQ * 4 + 2;
    float pg = gb[(nstart - 1) * 4];
    float pp = 1.0f / (1.0f + __expf((0.5f - ab[(nstart - 1) * 4]) * 10.0f));
    for (int n = nstart; n < n0 + 64; ++n) {
      float cg = gb[n * 4]; g += fabsf(cg - pg); pg = cg;
      float cp = 1.0f / (1.0f + __expf((0.5f - ab[n * 4]) * 10.0f));
      ps += fabsf(cp - pp); pp = cp;
    }
  }
  g  += __shfl_down(g, 4, 8);  g  += __shfl_down(g, 2, 8);  g  += __shfl_down(g, 1, 8);
  ps += __shfl_down(ps, 4, 8); ps += __shfl_down(ps, 2, 8); ps += __shfl_down(ps, 1, 8);

  if (seg == 0) {
    s_g[b]  = g;
    s_ps[b] = ps;
    s_kl[b] = fmaxf(-0.5f * s - 0.5f, 0.0f);
  }
  __syncthreads();

  if (t < 32) {
    float gv  = s_g[t];
    float kl  = s_kl[t];
    float d   = ptc[t] - gv;  float aux = d * d;
    float e   = s_ps[t] - gv; float tr  = e * e;
    kl  += __shfl_down(kl, 16, 32); aux += __shfl_down(aux, 16, 32); tr += __shfl_down(tr, 16, 32);
    kl  += __shfl_down(kl,  8, 32); aux += __shfl_down(aux,  8, 32); tr += __shfl_down(tr,  8, 32);
    kl  += __shfl_down(kl,  4, 32); aux += __shfl_down(aux,  4, 32); tr += __shfl_down(tr,  4, 32);
    kl  += __shfl_down(kl,  2, 32); aux += __shfl_down(aux,  2, 32); tr += __shfl_down(tr,  2, 32);
    kl  += __shfl_down(kl,  1, 32); aux += __shfl_down(aux,  1, 32); tr += __shfl_down(tr,  1, 32);
    if (t == 0) { ws[96] = kl; ws[97] = aux; ws[98] = tr; }
  }
  __syncthreads();
  if (t < 64) {
    TAIL_COMBINE();
  }
}

extern "C" void kernel_launch(void* const* d_in, const int* in_sizes, int n_in,
                              void* d_out, int out_size, void* d_ws, size_t ws_size,
                              hipStream_t stream) {
  const float* at  = (const float*)d_in[0];
  const float* mu  = (const float*)d_in[1];
  const float* lv  = (const float*)d_in[2];
  const float* ptc = (const float*)d_in[3];
  const float* gt  = (const float*)d_in[4];
  float* ws  = (float*)d_ws;
  float* out = (float*)d_out;

  // reset the last-block counter (ws[128]) each launch
  hipMemsetAsync((char*)d_ws + 128 * sizeof(float), 0, sizeof(unsigned), stream);
  sdtw_fused_kernel<<<97, 256, 0, stream>>>(at, mu, lv, ptc, gt, ws, out);
}

// Round 18
// 48.083 us; speedup vs baseline: 1.2077x; 1.2077x over previous
//
#include <hip/hip_runtime.h>
#include <hip/hip_bf16.h>

#define SEQ   512
#define LPAD  64
#define RPAD  68
#define TOT   (SEQ + LPAD + RPAD)   // 644 float4 per sequence
#define C1f   14.426950408889634f    // 1/(gamma*ln2), gamma=0.1
#define K1f   0.069314718055994531f  // gamma*ln2

#if __has_builtin(__builtin_amdgcn_exp2f)
#define EXP2(x) __builtin_amdgcn_exp2f(x)
#else
#define EXP2(x) exp2f(x)
#endif

#define SB() __builtin_amdgcn_sched_barrier(0)

__device__ __forceinline__ float cost4(float4 X, float4 Y) {
  return fabsf(X.x - Y.x) + fabsf(X.y - Y.y) + fabsf(X.z - Y.z) + fabsf(X.w - Y.w);
}

// f64 lane shifts via DPP wave shifts: VALU, 0-fill at edges (0 == exp-domain BIG).
__device__ __forceinline__ double dshr1(double x) {  // lane t <- lane t+1; lane63 <- 0
  int lo = __builtin_amdgcn_update_dpp(0, __double2loint(x), 0x138, 0xF, 0xF, true);
  int hi = __builtin_amdgcn_update_dpp(0, __double2hiint(x), 0x138, 0xF, 0xF, true);
  return __hiloint2double(hi, lo);
}
__device__ __forceinline__ double dshl1(double x) {  // lane t <- lane t-1; lane0 <- 0
  int lo = __builtin_amdgcn_update_dpp(0, __double2loint(x), 0x130, 0xF, 0xF, true);
  int hi = __builtin_amdgcn_update_dpp(0, __double2hiint(x), 0x130, 0xF, 0xF, true);
  return __hiloint2double(hi, lo);
}
__device__ __forceinline__ double pow2i(int k) {     // 2^k exactly, |k| <= ~500
  union { unsigned long long u; double d; } v;
  v.u = ((unsigned long long)(1023 + k)) << 52;
  return v.d;
}

// ---- 1 cell/lane, band u = t in [0,63]; f64 exp-domain DP (R14 algebra) ----
// pair n covers diags p=2n+1 (odd) and p=2n+2 (even).
//   odd  cell: i = n+t-31, j = n-t+32; neighbors: diag=dA, left=dB, up=dshl1(dB)
//   even cell: i = n+t-30, j = n-t+32; neighbors: diag=dB, up=nA, left=dshr1(nA)
// windows: X0 = x[n+t-31], X1 = x[n+t-30], Y0 = y[n-t+32]
// 6 rotating slots; pair m -> slot m%6. TWO pairs per SB scheduling region.
// Servo feedback runs every OTHER region (once per 4 pairs): the group bump
// is split across the even group's two COMPPs (so per-diag exp2f args stay
// ~<=110, same inf-margin as R14), queue depth 1.
#define DECLS(s) \
  float4 X0##s, X1##s, Y0##s; \
  double Po##s, Pe##s; \
  int k1##s, k2##s;

#define LOADW(s, m) do { \
    X0##s = pX[(m)]; X1##s = pX[(m) + 1]; Y0##s = pY[(m)]; } while (0)

// P factors for the pair in slot s with scale bump folded into the exp2 arg.
#define COMPP(s, bump) do { \
    k1##s = (bump) >> 1; k2##s = (bump) - k1##s; \
    float _f1 = (float)k1##s, _f2 = (float)k2##s; \
    Po##s = (double)EXP2(fmaf(cost4(X0##s, Y0##s), -C1f, _f1)); \
    Pe##s = (double)EXP2(fmaf(cost4(X1##s, Y0##s), -C1f, _f2)); } while (0)

// f64 recurrence for one pair; sp = previous pair's slot (supplies k2prev).
#define CHAIN(s, sp) do { \
    double _s2p = pow2i(k2##sp), _s1c = pow2i(k1##s); \
    double _up = dshl1(dB); \
    double _nA = Po##s * fma(dA, _s2p, dB + _up); \
    double _lf = dshr1(_nA); \
    double _nB = Pe##s * fma(dB, _s1c, _nA + _lf); \
    dA = _nA; dB = _nB; } while (0)

// servo feedback, cadence = every other region. The bump bq1 was consumed by
// THIS region's COMPPs (chains next region -> not yet visible in dB), so
// in-flight = bq1 and the new correction is def - bq1. Ktot counts bq1 here
// (the one place it is applied).
#define FEEDBACK2() do { \
    int _hib = __builtin_amdgcn_readlane(__double2hiint(dB), 31); \
    int _def = 1023 - ((_hib >> 20) & 0x7ff); \
    Ktot += bq1; \
    int _nb = _def - bq1; _nb = _nb < -440 ? -440 : (_nb > 440 ? 440 : _nb); \
    bq1 = _nb; } while (0)

// Even group (with servo): bump split across the two COMPPs.
#define GROUPF(A, B, C, D, E, F, m) do { \
    SB(); \
    LOADW(E, (m));     LOADW(F, (m) + 1); \
    { int _h1 = bq1 >> 1, _h2 = bq1 - _h1; \
      COMPP(C, _h1);   COMPP(D, _h2); } \
    CHAIN(A, F);       CHAIN(B, A); \
    FEEDBACK2(); } while (0)

// Odd group: no bump, no feedback.
#define GROUPN(A, B, C, D, E, F, m) do { \
    SB(); \
    LOADW(E, (m));     LOADW(F, (m) + 1); \
    COMPP(C, 0);       COMPP(D, 0); \
    CHAIN(A, F);       CHAIN(B, A); } while (0)

// Blocks 0..95: banded soft-DTW per extended batch element -> ws[b].
// Block 96: KL + transition-count losses -> ws[96..98]. Runs concurrently.
__global__ __launch_bounds__(256, 1) void sdtw_fused_kernel(
    const float* __restrict__ at,    // [32,512,4]
    const float* __restrict__ mu,    // [32,64]
    const float* __restrict__ lv,    // [32,64]
    const float* __restrict__ ptc,   // [32,1]
    const float* __restrict__ gt,    // [32,512,4]
    float* __restrict__ ws)          // [0..95]=v, [96]=klS, [97]=auxS, [98]=trS
{
  __shared__ float4 sx[TOT];
  __shared__ float4 sy[TOT];
  __shared__ float s_g[32], s_ps[32], s_kl[32];

  const int blk = blockIdx.x;
  const int t   = threadIdx.x;

  if (blk < 96) {
    const float* xs;
    const float* ys;
    if (blk < 32)      { xs = at + (size_t)blk        * SEQ * 4; ys = gt + (size_t)blk * SEQ * 4; }
    else if (blk < 64) { xs = at + (size_t)(blk - 32) * SEQ * 4; ys = xs; }
    else               { xs = gt + (size_t)(blk - 64) * SEQ * 4; ys = xs; }

    for (int i = t; i < LPAD; i += 256) {
      sx[i] = make_float4(0.f, 0.f, 0.f, 0.f);
      sy[i] = make_float4(0.f, 0.f, 0.f, 0.f);
    }
    for (int i = LPAD + SEQ + t; i < TOT; i += 256) {
      sx[i] = make_float4(0.f, 0.f, 0.f, 0.f);
      sy[i] = make_float4(0.f, 0.f, 0.f, 0.f);
    }
    for (int i = t; i < SEQ; i += 256) {
      sx[LPAD + i] = ((const float4*)xs)[i];
      sy[LPAD + i] = ((const float4*)ys)[i];
    }
    __syncthreads();
    if (t >= 64) return;   // single wave runs the wavefront; no more barriers

    const float4* sxp = sx + LPAD;
    const float4* syp = sy + LPAD;
    const float4* pX = sxp + (t - 31);   // pX[m] = x[m+t-31]
    const float4* pY = syp + (32 - t);   // pY[m] = y[m-t+32]

    // seed: diag 0 = (0,0) at lane31 (even diag of pair -1; its slot is 5, k2_5=0)
    float a0 = -C1f * cost4(sxp[0], syp[0]);
    int   n0 = (int)floorf(a0);
    double e00 = (double)EXP2(a0 - (float)n0);
    double dA = 0.0;
    double dB = (t == 31) ? e00 : 0.0;
    int Ktot = -n0;
    int bq1 = 0;

    DECLS(0) DECLS(1) DECLS(2) DECLS(3) DECLS(4) DECLS(5)
    k25 = 0;   // pair -1's even bump (read by CHAIN(0,5) in group 0)
    k15 = 0;

    // prologue: windows for pairs 0..3; P for pairs 0,1 (bumps 0)
    LOADW(0, 0); LOADW(1, 1); LOADW(2, 2); LOADW(3, 3);
    COMPP(0, 0); COMPP(1, 0);

    // steady: groups k=0..251 in the loop (6 groups / iter; slot period 3,
    // feedback period 2 -> combined period 6), then tail groups 252..254.
    #pragma unroll 1
    for (int g = 0; g < 42; ++g) {
      const int m = 12 * g;
      GROUPF(0, 1, 2, 3, 4, 5, m + 4);    // k = 6g
      GROUPN(2, 3, 4, 5, 0, 1, m + 6);    // k = 6g+1
      GROUPF(4, 5, 0, 1, 2, 3, m + 8);    // k = 6g+2
      GROUPN(0, 1, 2, 3, 4, 5, m + 10);   // k = 6g+3
      GROUPF(2, 3, 4, 5, 0, 1, m + 12);   // k = 6g+4
      GROUPN(4, 5, 0, 1, 2, 3, m + 14);   // k = 6g+5
    }
    GROUPF(0, 1, 2, 3, 4, 5, 508);        // k = 252 (chains 504,505)
    GROUPN(2, 3, 4, 5, 0, 1, 510);        // k = 253 (chains 506,507)
    GROUPF(4, 5, 0, 1, 2, 3, 512);        // k = 254 (chains 508,509; COMPP 510)
    // epilogue: pair 510 (slot 0; prev pair 509 in slot 5). Its bump was
    // consumed and Ktot-counted in k=254's GROUPF.
    SB();
    CHAIN(0, 5);

    if (t == 31) {
      // final cell (511,511) = even diag of pair 510, lane31
      // v = -gamma*ln(E_true) = -K1f*(log2(stored) - Ktot)
      unsigned long long bits = __double_as_longlong(dB);
      int ee = (int)((bits >> 52) & 0x7ffull);
      double mant = __longlong_as_double((bits & 0xFFFFFFFFFFFFFull) | (1023ull << 52));
      double l2 = (double)(ee - 1023) + (double)__log2f((float)mant);
      ws[blk] = (float)(-(double)K1f * (l2 - (double)Ktot));
    }
    return;
  }

  // ---------- loss block (blk == 96), 256 threads: 8 per batch element ----------
  const int b = t >> 3, seg = t & 7;

  float s = 0.f;
  {
    const float* mb = mu + b * 64 + seg * 8;
    const float* lb = lv + b * 64 + seg * 8;
    #pragma unroll
    for (int z = 0; z < 8; ++z) {
      float m = mb[z], l = lb[z];
      s += 1.0f + l - m * m - __expf(l);
    }
  }
  s += __shfl_down(s, 4, 8);
  s += __shfl_down(s, 2, 8);
  s += __shfl_down(s, 1, 8);

  float g = 0.f, ps = 0.f;
  {
    const int n0 = seg * 64;
    const int nstart = (seg == 0) ? 1 : n0;
    const float* gb = gt + (size_t)b * SEQ * 4 + 2;
    const float* ab = at + (size_t)b * SEQ * 4 + 2;
    float pg = gb[(nstart - 1) * 4];
    float pp = 1.0f / (1.0f + __expf((0.5f - ab[(nstart - 1) * 4]) * 10.0f));
    for (int n = nstart; n < n0 + 64; ++n) {
      float cg = gb[n * 4]; g += fabsf(cg - pg); pg = cg;
      float cp = 1.0f / (1.0f + __expf((0.5f - ab[n * 4]) * 10.0f));
      ps += fabsf(cp - pp); pp = cp;
    }
  }
  g  += __shfl_down(g, 4, 8);  g  += __shfl_down(g, 2, 8);  g  += __shfl_down(g, 1, 8);
  ps += __shfl_down(ps, 4, 8); ps += __shfl_down(ps, 2, 8); ps += __shfl_down(ps, 1, 8);

  if (seg == 0) {
    s_g[b]  = g;
    s_ps[b] = ps;
    s_kl[b] = fmaxf(-0.5f * s - 0.5f, 0.0f);
  }
  __syncthreads();

  if (t < 32) {
    float gv  = s_g[t];
    float kl  = s_kl[t];
    float d   = ptc[t] - gv;  float aux = d * d;
    float e   = s_ps[t] - gv; float tr  = e * e;
    kl  += __shfl_down(kl, 16, 32); aux += __shfl_down(aux, 16, 32); tr += __shfl_down(tr, 16, 32);
    kl  += __shfl_down(kl,  8, 32); aux += __shfl_down(aux,  8, 32); tr += __shfl_down(tr,  8, 32);
    kl  += __shfl_down(kl,  4, 32); aux += __shfl_down(aux,  4, 32); tr += __shfl_down(tr,  4, 32);
    kl  += __shfl_down(kl,  2, 32); aux += __shfl_down(aux,  2, 32); tr += __shfl_down(tr,  2, 32);
    kl  += __shfl_down(kl,  1, 32); aux += __shfl_down(aux,  1, 32); tr += __shfl_down(tr,  1, 32);
    if (t == 0) { ws[96] = kl; ws[97] = aux; ws[98] = tr; }
  }
}

__global__ __launch_bounds__(64) void sdtw_combine_kernel(
    const float* __restrict__ ws, float* __restrict__ out)
{
  const int t = threadIdx.x;
  float vn = 0.f;
  if (t < 32) vn = ws[t] - 0.5f * (ws[32 + t] + ws[64 + t]);
  vn += __shfl_down(vn, 16, 32);
  vn += __shfl_down(vn,  8, 32);
  vn += __shfl_down(vn,  4, 32);
  vn += __shfl_down(vn,  2, 32);
  vn += __shfl_down(vn,  1, 32);
  if (t == 0) {
    float recon = vn * (1.0f / 1024.0f);   // mean(diag(v)) = sum/1024
    float kl    = ws[96] * (1.0f / 32.0f);
    float aux   = ws[97] * (1.0f / 32.0f);
    float tr    = ws[98] * (1.0f / 32.0f);
    out[0] = recon + kl + 0.1f * aux + 0.5f * tr;
    out[1] = recon;
    out[2] = kl;
    out[3] = aux;
    out[4] = tr;
  }
}

extern "C" void kernel_launch(void* const* d_in, const int* in_sizes, int n_in,
                              void* d_out, int out_size, void* d_ws, size_t ws_size,
                              hipStream_t stream) {
  const float* at  = (const float*)d_in[0];
  const float* mu  = (const float*)d_in[1];
  const float* lv  = (const float*)d_in[2];
  const float* ptc = (const float*)d_in[3];
  const float* gt  = (const float*)d_in[4];
  float* ws  = (float*)d_ws;
  float* out = (float*)d_out;

  sdtw_fused_kernel<<<97, 256, 0, stream>>>(at, mu, lv, ptc, gt, ws);
  sdtw_combine_kernel<<<1, 64, 0, stream>>>(ws, out);
}